// Round 4
// baseline (2040.087 us; speedup 1.0000x reference)
//
#include <hip/hip_runtime.h>
#include <limits.h>

#define CDIM 256
#define KDIM 8192
#define NROWS 32768
#define THW 8192
#define BN 64      // rows per block

// ws layout (bytes):
//   [0,       8388608)  wT[c][k] = w[k][c]  (256 x 8192 f32)
//   [8388608, 8519680)  A[n]  = np-pairwise fp32 sum z_flat[n]^2 (32768 f32)
//   [8519680, 8552448)  Cq[k] = np-pairwise fp32 sum w[k]^2      (8192 f32)
//   [8552448, 8683520)  idx_i (32768 i32)
//   [8683520, 8685568)  loss partials (512 f32)

__device__ __forceinline__ float sq_rn(float a) { return __fmul_rn(a, a); }

// numpy pairwise sum of 128 fp32 squares, AVX512 model (verified round 3).
__device__ float pairwise128_sq(const float* __restrict__ p, int stride) {
    float s[16];
#pragma unroll
    for (int l = 0; l < 16; ++l) {
        const float a0 = sq_rn(p[(l)*stride]);
        const float a1 = sq_rn(p[(16 + l) * stride]);
        const float a2 = sq_rn(p[(32 + l) * stride]);
        const float a3 = sq_rn(p[(48 + l) * stride]);
        const float a4 = sq_rn(p[(64 + l) * stride]);
        const float a5 = sq_rn(p[(80 + l) * stride]);
        const float a6 = sq_rn(p[(96 + l) * stride]);
        const float a7 = sq_rn(p[(112 + l) * stride]);
        s[l] = __fadd_rn(__fadd_rn(__fadd_rn(a0, a1), __fadd_rn(a2, a3)),
                         __fadd_rn(__fadd_rn(a4, a5), __fadd_rn(a6, a7)));
    }
    const float u0 = __fadd_rn(__fadd_rn(s[0], s[8]),  __fadd_rn(s[4], s[12]));
    const float u1 = __fadd_rn(__fadd_rn(s[1], s[9]),  __fadd_rn(s[5], s[13]));
    const float u2 = __fadd_rn(__fadd_rn(s[2], s[10]), __fadd_rn(s[6], s[14]));
    const float u3 = __fadd_rn(__fadd_rn(s[3], s[11]), __fadd_rn(s[7], s[15]));
    return __fadd_rn(__fadd_rn(u0, u2), __fadd_rn(u1, u3));
}

__global__ __launch_bounds__(256) void k_A(const float* __restrict__ z,
                                           float* __restrict__ A) {
    const int n = blockIdx.x * 256 + threadIdx.x;
    const float* zp = z + (size_t)(n >> 13) * (CDIM * THW) + (n & (THW - 1));
    const float b0 = pairwise128_sq(zp, THW);
    const float b1 = pairwise128_sq(zp + (size_t)128 * THW, THW);
    A[n] = __fadd_rn(b0, b1);
}

__global__ __launch_bounds__(256) void k_C(const float* __restrict__ w,
                                           float* __restrict__ Cq) {
    const int k = blockIdx.x * 256 + threadIdx.x;
    const float* wp = w + (size_t)k * CDIM;
    Cq[k] = __fadd_rn(pairwise128_sq(wp, 1), pairwise128_sq(wp + 128, 1));
}

// Transpose w[k][c] -> wT[c][k] via 64x64 LDS tiles.
__global__ __launch_bounds__(256) void k_T(const float* __restrict__ w,
                                           float* __restrict__ wT) {
    __shared__ float tile[64][65];
    const int t = threadIdx.x;
    const int kt = blockIdx.x >> 2;
    const int ct = blockIdx.x & 3;
    const int k0 = kt * 64, c0 = ct * 64;
    const int rg = t >> 4, cl = (t & 15) * 4;
#pragma unroll
    for (int i = 0; i < 4; ++i) {
        const int r = rg + i * 16;
        float4 v = *reinterpret_cast<const float4*>(w + (size_t)(k0 + r) * CDIM + c0 + cl);
        tile[r][cl] = v.x; tile[r][cl + 1] = v.y;
        tile[r][cl + 2] = v.z; tile[r][cl + 3] = v.w;
    }
    __syncthreads();
#pragma unroll
    for (int i = 0; i < 4; ++i) {
        const int cr = rg + i * 16;
        float4 o;
        o.x = tile[cl + 0][cr]; o.y = tile[cl + 1][cr];
        o.z = tile[cl + 2][cr]; o.w = tile[cl + 3][cr];
        *reinterpret_cast<float4*>(wT + (size_t)(c0 + cr) * KDIM + k0 + cl) = o;
    }
}

// Fused scores GEMM + argmin, np-fp32-exact (model verified round 3):
//   M[n][k] = single ascending-c fmaf chain; d = RN(RN(A - 2M) + Cq);
//   argmin ascending k, strict <, ties -> lowest index.
// w streamed from global wT (L2) in registers; z LDS-resident. No inner barriers.
#define PREF_W(buf, p) { \
    const int pp = (p) & 4095; \
    const float* ap = wT + (size_t)(pp & 63) * (4 * KDIM) + ((pp >> 6) * 128) + tcol8; \
    buf[0] = *(const float4*)(ap);            buf[1] = *(const float4*)(ap + 4); \
    buf[2] = *(const float4*)(ap + KDIM);     buf[3] = *(const float4*)(ap + KDIM + 4); \
    buf[4] = *(const float4*)(ap + 2 * KDIM); buf[5] = *(const float4*)(ap + 2 * KDIM + 4); \
    buf[6] = *(const float4*)(ap + 3 * KDIM); buf[7] = *(const float4*)(ap + 3 * KDIM + 4); }

#define PREF_Z(buf, p) { \
    const int cz = ((p) & 63) * 4; \
    buf[0] = *(const float4*)(&zt[cz][trow4]); \
    buf[1] = *(const float4*)(&zt[cz + 1][trow4]); \
    buf[2] = *(const float4*)(&zt[cz + 2][trow4]); \
    buf[3] = *(const float4*)(&zt[cz + 3][trow4]); }

#define COMP(wbuf, zbuf) { \
    _Pragma("unroll") \
    for (int q = 0; q < 4; ++q) { \
        const float zr[4] = {zbuf[q].x, zbuf[q].y, zbuf[q].z, zbuf[q].w}; \
        const float wr[8] = {wbuf[2*q].x, wbuf[2*q].y, wbuf[2*q].z, wbuf[2*q].w, \
                             wbuf[2*q+1].x, wbuf[2*q+1].y, wbuf[2*q+1].z, wbuf[2*q+1].w}; \
        _Pragma("unroll") \
        for (int r = 0; r < 4; ++r) \
            _Pragma("unroll") \
            for (int j = 0; j < 8; ++j) \
                acc[r][j] = fmaf(zr[r], wr[j], acc[r][j]); \
    } }

__global__ __launch_bounds__(256) void k_argmin(
    const float* __restrict__ z, const float* __restrict__ wT,
    const float* __restrict__ A, const float* __restrict__ Cq,
    float* __restrict__ idx_f, int* __restrict__ idx_i)
{
    __shared__ float zt[CDIM][BN];   // 64 KB resident z tile [c][n]

    const int t = threadIdx.x;
    const int blk = blockIdx.x;
    const int b = (blk * BN) >> 13;
    const int s0 = (blk * BN) & (THW - 1);
    const float* zb = z + (size_t)b * (CDIM * THW) + s0;

    {
        const int lane = t & 15;
        const int c0 = t >> 4;
#pragma unroll
        for (int it = 0; it < 16; ++it) {
            const int c = c0 + it * 16;
            float4 v = *reinterpret_cast<const float4*>(zb + (size_t)c * THW + lane * 4);
            *reinterpret_cast<float4*>(&zt[c][lane * 4]) = v;
        }
    }
    __syncthreads();

    const int tcol = t & 15;        // code group: k = kc*128 + tcol*8 + j
    const int trow = t >> 4;        // row group:  n = blk*BN + trow*4 + r
    const int tcol8 = tcol * 8;
    const int trow4 = trow * 4;

    float Areg[4];
#pragma unroll
    for (int r = 0; r < 4; ++r) Areg[r] = A[blk * BN + trow4 + r];

    float best[4];
    int bidx[4];
#pragma unroll
    for (int r = 0; r < 4; ++r) { best[r] = 3.0e38f; bidx[r] = INT_MAX; }

    float4 wa[8], wb[8], za[4], zb4[4];
    PREF_W(wa, 0); PREF_Z(za, 0);

    for (int kc = 0; kc < 64; ++kc) {
        float acc[4][8];
#pragma unroll
        for (int r = 0; r < 4; ++r)
#pragma unroll
            for (int j = 0; j < 8; ++j) acc[r][j] = 0.f;

        // epilogue constants prefetched early (long vmcnt distance, no drain)
        const float4 cq0 = *reinterpret_cast<const float4*>(Cq + kc * 128 + tcol8);
        const float4 cq1 = *reinterpret_cast<const float4*>(Cq + kc * 128 + tcol8 + 4);

        const int pbase = kc * 64;
        for (int cg = 0; cg < 64; cg += 2) {
            PREF_W(wb, pbase + cg + 1); PREF_Z(zb4, pbase + cg + 1);
            COMP(wa, za);
            PREF_W(wa, pbase + cg + 2); PREF_Z(za, pbase + cg + 2);
            COMP(wb, zb4);
        }

        const float cv[8] = {cq0.x, cq0.y, cq0.z, cq0.w, cq1.x, cq1.y, cq1.z, cq1.w};
#pragma unroll
        for (int j = 0; j < 8; ++j) {
            const int kg = kc * 128 + tcol8 + j;
#pragma unroll
            for (int r = 0; r < 4; ++r) {
                const float dd = __fadd_rn(__fadd_rn(Areg[r], -2.0f * acc[r][j]), cv[j]);
                if (dd < best[r]) { best[r] = dd; bidx[r] = kg; }
            }
        }
    }

    // Merge across the 16 code-groups; ties -> lower global index.
#pragma unroll
    for (int m = 1; m < 16; m <<= 1) {
#pragma unroll
        for (int r = 0; r < 4; ++r) {
            const float od = __shfl_xor(best[r], m, 64);
            const int oi = __shfl_xor(bidx[r], m, 64);
            if (od < best[r] || (od == best[r] && oi < bidx[r])) {
                best[r] = od; bidx[r] = oi;
            }
        }
    }
    if (tcol == 0) {
#pragma unroll
        for (int r = 0; r < 4; ++r) {
            const int n = blk * BN + trow4 + r;
            idx_f[n] = (float)bidx[r];
            idx_i[n] = bidx[r];
        }
    }
}

// Gather z_q = w[idx], transpose to [B,C,T,H,W], accumulate sum((z_q - z)^2).
__global__ __launch_bounds__(256, 2) void k_out(
    const float* __restrict__ w, const float* __restrict__ z,
    const int* __restrict__ idx, float* __restrict__ out0,
    float* __restrict__ partial)
{
    __shared__ float q[CDIM][BN + 1];
    __shared__ int si[BN];
    __shared__ float red[256];

    const int t = threadIdx.x;
    const int blk = blockIdx.x;
    const int n0 = blk * BN;
    const int b = n0 >> 13;
    const int s0 = n0 & (THW - 1);

    if (t < BN) si[t] = idx[n0 + t];
    __syncthreads();

    {
        const int c = t;
#pragma unroll 4
        for (int i = 0; i < BN; ++i)
            q[c][i] = w[(size_t)si[i] * CDIM + c];
    }
    __syncthreads();

    const int sl = t & 63;
    const int cb = t >> 6;
    float lacc = 0.f;
    const size_t base = (size_t)b * (CDIM * THW) + s0 + sl;
#pragma unroll 4
    for (int j = 0; j < 64; ++j) {
        const int c = cb * 64 + j;
        const float qv = q[c][sl];
        const size_t a = base + (size_t)c * THW;
        const float zv = z[a];
        out0[a] = qv;
        const float d = qv - zv;
        lacc = fmaf(d, d, lacc);
    }
    red[t] = lacc;
    __syncthreads();
    for (int mm = 128; mm > 0; mm >>= 1) {
        if (t < mm) red[t] += red[t + mm];
        __syncthreads();
    }
    if (t == 0) partial[blk] = red[0];
}

__global__ __launch_bounds__(256) void k_loss(const float* __restrict__ partial,
                                              float* __restrict__ out_loss) {
    __shared__ double red[256];
    const int t = threadIdx.x;
    double a = 0.0;
    for (int i = t; i < NROWS / BN; i += 256) a += (double)partial[i];
    red[t] = a;
    __syncthreads();
    for (int mm = 128; mm > 0; mm >>= 1) {
        if (t < mm) red[t] += red[t + mm];
        __syncthreads();
    }
    if (t == 0) out_loss[0] = (float)(1.25 * red[0] / 8388608.0);
}

extern "C" void kernel_launch(void* const* d_in, const int* in_sizes, int n_in,
                              void* d_out, int out_size, void* d_ws, size_t ws_size,
                              hipStream_t stream) {
    const float* z = (const float*)d_in[0];
    const float* w = (const float*)d_in[1];
    float* out = (float*)d_out;

    char* ws = (char*)d_ws;
    float* wT = (float*)ws;                     // 8 MB
    float* A = (float*)(ws + 8388608);          // 128 KB
    float* Cq = (float*)(ws + 8519680);         // 32 KB
    int* idxi = (int*)(ws + 8552448);           // 128 KB
    float* partial = (float*)(ws + 8683520);    // 2 KB

    float* out_zq = out;                 // [B,C,T,H,W] = 8388608
    float* out_loss = out + 8388608;     // scalar
    float* out_idx = out + 8388609;      // [B,T,H,W] = 32768, as float

    k_T<<<512, 256, 0, stream>>>(w, wT);
    k_A<<<NROWS / 256, 256, 0, stream>>>(z, A);
    k_C<<<KDIM / 256, 256, 0, stream>>>(w, Cq);
    k_argmin<<<NROWS / BN, 256, 0, stream>>>(z, wT, A, Cq, out_idx, idxi);
    k_out<<<NROWS / BN, 256, 0, stream>>>(w, z, idxi, out_zq, partial);
    k_loss<<<1, 256, 0, stream>>>(partial, out_loss);
}

// Round 5
// 1674.315 us; speedup vs baseline: 1.2185x; 1.2185x over previous
//
#include <hip/hip_runtime.h>
#include <limits.h>

#define CDIM 256
#define KDIM 8192
#define NROWS 32768
#define THW 8192
#define BN 64      // rows per block
#define BK 512     // codes per k-tile
#define CCH 4      // channels per staged chunk
#define NKT (KDIM / BK)          // 16 k-tiles
#define NCC (CDIM / CCH)         // 64 chunks per k-tile

// ws layout (bytes):
//   [0,       8388608)  wT[c][k] = w[k][c]  (256 x 8192 f32)
//   [8388608, 8519680)  A[n]  (32768 f32)
//   [8519680, 8552448)  Cq[k] (8192 f32)
//   [8552448, 8683520)  idx_i (32768 i32)
//   [8683520, 8685568)  loss partials (512 f32)

__device__ __forceinline__ float sq_rn(float a) { return __fmul_rn(a, a); }

__device__ __forceinline__ void gl_lds16(const float* g, float* l) {
    __builtin_amdgcn_global_load_lds(
        (const __attribute__((address_space(1))) unsigned int*)(g),
        (__attribute__((address_space(3))) unsigned int*)(l), 16, 0, 0);
}

// numpy pairwise sum of 128 fp32 squares, AVX512 model (verified round 3).
__device__ float pairwise128_sq(const float* __restrict__ p, int stride) {
    float s[16];
#pragma unroll
    for (int l = 0; l < 16; ++l) {
        const float a0 = sq_rn(p[(l)*stride]);
        const float a1 = sq_rn(p[(16 + l) * stride]);
        const float a2 = sq_rn(p[(32 + l) * stride]);
        const float a3 = sq_rn(p[(48 + l) * stride]);
        const float a4 = sq_rn(p[(64 + l) * stride]);
        const float a5 = sq_rn(p[(80 + l) * stride]);
        const float a6 = sq_rn(p[(96 + l) * stride]);
        const float a7 = sq_rn(p[(112 + l) * stride]);
        s[l] = __fadd_rn(__fadd_rn(__fadd_rn(a0, a1), __fadd_rn(a2, a3)),
                         __fadd_rn(__fadd_rn(a4, a5), __fadd_rn(a6, a7)));
    }
    const float u0 = __fadd_rn(__fadd_rn(s[0], s[8]),  __fadd_rn(s[4], s[12]));
    const float u1 = __fadd_rn(__fadd_rn(s[1], s[9]),  __fadd_rn(s[5], s[13]));
    const float u2 = __fadd_rn(__fadd_rn(s[2], s[10]), __fadd_rn(s[6], s[14]));
    const float u3 = __fadd_rn(__fadd_rn(s[3], s[11]), __fadd_rn(s[7], s[15]));
    return __fadd_rn(__fadd_rn(u0, u2), __fadd_rn(u1, u3));
}

__global__ __launch_bounds__(256) void k_A(const float* __restrict__ z,
                                           float* __restrict__ A) {
    const int n = blockIdx.x * 256 + threadIdx.x;
    const float* zp = z + (size_t)(n >> 13) * (CDIM * THW) + (n & (THW - 1));
    const float b0 = pairwise128_sq(zp, THW);
    const float b1 = pairwise128_sq(zp + (size_t)128 * THW, THW);
    A[n] = __fadd_rn(b0, b1);
}

__global__ __launch_bounds__(256) void k_C(const float* __restrict__ w,
                                           float* __restrict__ Cq) {
    const int k = blockIdx.x * 256 + threadIdx.x;
    const float* wp = w + (size_t)k * CDIM;
    Cq[k] = __fadd_rn(pairwise128_sq(wp, 1), pairwise128_sq(wp + 128, 1));
}

// Transpose w[k][c] -> wT[c][k] via 64x64 LDS tiles.
__global__ __launch_bounds__(256) void k_T(const float* __restrict__ w,
                                           float* __restrict__ wT) {
    __shared__ float tile[64][65];
    const int t = threadIdx.x;
    const int kt = blockIdx.x >> 2;
    const int ct = blockIdx.x & 3;
    const int k0 = kt * 64, c0 = ct * 64;
    const int rg = t >> 4, cl = (t & 15) * 4;
#pragma unroll
    for (int i = 0; i < 4; ++i) {
        const int r = rg + i * 16;
        float4 v = *reinterpret_cast<const float4*>(w + (size_t)(k0 + r) * CDIM + c0 + cl);
        tile[r][cl] = v.x; tile[r][cl + 1] = v.y;
        tile[r][cl + 2] = v.z; tile[r][cl + 3] = v.w;
    }
    __syncthreads();
#pragma unroll
    for (int i = 0; i < 4; ++i) {
        const int cr = rg + i * 16;
        float4 o;
        o.x = tile[cl + 0][cr]; o.y = tile[cl + 1][cr];
        o.z = tile[cl + 2][cr]; o.w = tile[cl + 3][cr];
        *reinterpret_cast<float4*>(wT + (size_t)(c0 + cr) * KDIM + k0 + cl) = o;
    }
}

// Stage chunk (kt, cc) of wT into wt[buf] via global_load_lds (16B).
// LDS layout per c-row (512 codes = 128 float4 slots): slot sr = q*32 + tc
// holds k = tc*16 + q*4 .. +3  (q-split -> compute reads at 16B stride,
// conflict-free at LDS BW floor). 8 groups of 64 slots; group g staged by
// wave g>>1, issue g&1; lds dest = uniform base + lane*16 (HW rule).
#define STAGE(buf, kt_, cc_) { \
    const int lane_ = t & 63; \
    const int wv_ = t >> 6; \
    _Pragma("unroll") \
    for (int i_ = 0; i_ < 2; ++i_) { \
        const int g_ = wv_ * 2 + i_; \
        const int s_ = g_ * 64 + lane_; \
        const int ci_ = s_ >> 7; \
        const int sr_ = s_ & 127; \
        const int q_ = sr_ >> 5; \
        const int tc_ = sr_ & 31; \
        const float* src_ = wT + (size_t)((cc_) * CCH + ci_) * KDIM \
                            + (kt_) * BK + tc_ * 16 + q_ * 4; \
        gl_lds16(src_, &wt[buf][g_ * 256]); \
    } }

// Fused scores GEMM + argmin, np-fp32-exact (verified round 3):
// single ascending-c fmaf chain; d = RN(RN(A-2M)+Cq); argmin ties->lowest k.
// 8 rows x 16 cols per thread; w double-buffered in LDS via global_load_lds.
__global__ __launch_bounds__(256, 2) void k_argmin(
    const float* __restrict__ z, const float* __restrict__ wT,
    const float* __restrict__ A, const float* __restrict__ Cq,
    float* __restrict__ idx_f, int* __restrict__ idx_i)
{
    __shared__ float zt[CDIM][BN];    // 64 KB resident z tile [c][n]
    __shared__ float wt[2][CCH * BK]; // 2 x 8 KB w chunk double-buffer

    const int t = threadIdx.x;
    const int blk = blockIdx.x;
    const int b = (blk * BN) >> 13;
    const int s0 = (blk * BN) & (THW - 1);
    const float* zb = z + (size_t)b * (CDIM * THW) + s0;

    {   // load z tile (coalesced, once)
        const int lane = t & 15;
        const int c0 = t >> 4;
#pragma unroll
        for (int it = 0; it < 16; ++it) {
            const int c = c0 + it * 16;
            float4 v = *reinterpret_cast<const float4*>(zb + (size_t)c * THW + lane * 4);
            *reinterpret_cast<float4*>(&zt[c][lane * 4]) = v;
        }
    }
    STAGE(0, 0, 0);
    __syncthreads();   // publish zt + wt[0] chunk 0

    const int tcol = t & 31;   // code group: k = kt*BK + tcol*16 + j
    const int trow = t >> 5;   // row group:  n = blk*BN + trow*8 + r

    float Areg[8];
#pragma unroll
    for (int r = 0; r < 8; ++r) Areg[r] = A[blk * BN + trow * 8 + r];

    float best[8];
    int bidx[8];
#pragma unroll
    for (int r = 0; r < 8; ++r) { best[r] = 3.0e38f; bidx[r] = INT_MAX; }

    int par = 0;
    for (int kt = 0; kt < NKT; ++kt) {
        float acc[8][16];
#pragma unroll
        for (int r = 0; r < 8; ++r)
#pragma unroll
            for (int j = 0; j < 16; ++j) acc[r][j] = 0.f;

        // epilogue constants: long-distance prefetch, L2-hot
        float4 cq[4];
#pragma unroll
        for (int q = 0; q < 4; ++q)
            cq[q] = *reinterpret_cast<const float4*>(Cq + kt * BK + tcol * 16 + q * 4);

        for (int cc = 0; cc < NCC; ++cc) {
            const int gnext = kt * NCC + cc + 1;
            if (gnext < NKT * NCC) {
                const int nkt = gnext >> 6;
                const int ncc = gnext & 63;
                STAGE(par ^ 1, nkt, ncc);   // overlap with compute below
            }
            const float* wch = wt[par];
            const int cbase = cc * CCH;
#pragma unroll
            for (int c = 0; c < CCH; ++c) {
                const float4 z0 = *reinterpret_cast<const float4*>(&zt[cbase + c][trow * 8]);
                const float4 z1 = *reinterpret_cast<const float4*>(&zt[cbase + c][trow * 8 + 4]);
                float4 wv[4];
#pragma unroll
                for (int q = 0; q < 4; ++q)
                    wv[q] = *reinterpret_cast<const float4*>(&wch[c * 512 + q * 128 + tcol * 4]);
                const float zr[8] = {z0.x, z0.y, z0.z, z0.w, z1.x, z1.y, z1.z, z1.w};
                const float wr[16] = {wv[0].x, wv[0].y, wv[0].z, wv[0].w,
                                      wv[1].x, wv[1].y, wv[1].z, wv[1].w,
                                      wv[2].x, wv[2].y, wv[2].z, wv[2].w,
                                      wv[3].x, wv[3].y, wv[3].z, wv[3].w};
#pragma unroll
                for (int r = 0; r < 8; ++r)
#pragma unroll
                    for (int j = 0; j < 16; ++j)
                        acc[r][j] = fmaf(zr[r], wr[j], acc[r][j]);
            }
            __syncthreads();   // drain own stage (covered by compute), publish
            par ^= 1;
        }

        // epilogue: d = RN(RN(A - 2M) + C); ascending k; strict < (np.argmin)
#pragma unroll
        for (int j = 0; j < 16; ++j) {
            const int kg = kt * BK + tcol * 16 + j;
            const float cv = ((const float*)&cq[j >> 2])[j & 3];
#pragma unroll
            for (int r = 0; r < 8; ++r) {
                const float dd = __fadd_rn(__fadd_rn(Areg[r], -2.0f * acc[r][j]), cv);
                if (dd < best[r]) { best[r] = dd; bidx[r] = kg; }
            }
        }
    }

    // Merge across the 32 code-groups (lane low 5 bits); ties -> lower k.
#pragma unroll
    for (int m = 1; m < 32; m <<= 1) {
#pragma unroll
        for (int r = 0; r < 8; ++r) {
            const float od = __shfl_xor(best[r], m, 64);
            const int oi = __shfl_xor(bidx[r], m, 64);
            if (od < best[r] || (od == best[r] && oi < bidx[r])) {
                best[r] = od; bidx[r] = oi;
            }
        }
    }
    if (tcol == 0) {
#pragma unroll
        for (int r = 0; r < 8; ++r) {
            const int n = blk * BN + trow * 8 + r;
            idx_f[n] = (float)bidx[r];
            idx_i[n] = bidx[r];
        }
    }
}

// Gather z_q = w[idx], transpose to [B,C,T,H,W], accumulate sum((z_q - z)^2).
__global__ __launch_bounds__(256, 2) void k_out(
    const float* __restrict__ w, const float* __restrict__ z,
    const int* __restrict__ idx, float* __restrict__ out0,
    float* __restrict__ partial)
{
    __shared__ float q[CDIM][BN + 1];
    __shared__ int si[BN];
    __shared__ float red[256];

    const int t = threadIdx.x;
    const int blk = blockIdx.x;
    const int n0 = blk * BN;
    const int b = n0 >> 13;
    const int s0 = n0 & (THW - 1);

    if (t < BN) si[t] = idx[n0 + t];
    __syncthreads();

    {
        const int c = t;
#pragma unroll 4
        for (int i = 0; i < BN; ++i)
            q[c][i] = w[(size_t)si[i] * CDIM + c];
    }
    __syncthreads();

    const int sl = t & 63;
    const int cb = t >> 6;
    float lacc = 0.f;
    const size_t base = (size_t)b * (CDIM * THW) + s0 + sl;
#pragma unroll 4
    for (int j = 0; j < 64; ++j) {
        const int c = cb * 64 + j;
        const float qv = q[c][sl];
        const size_t a = base + (size_t)c * THW;
        const float zv = z[a];
        out0[a] = qv;
        const float d = qv - zv;
        lacc = fmaf(d, d, lacc);
    }
    red[t] = lacc;
    __syncthreads();
    for (int mm = 128; mm > 0; mm >>= 1) {
        if (t < mm) red[t] += red[t + mm];
        __syncthreads();
    }
    if (t == 0) partial[blk] = red[0];
}

__global__ __launch_bounds__(256) void k_loss(const float* __restrict__ partial,
                                              float* __restrict__ out_loss) {
    __shared__ double red[256];
    const int t = threadIdx.x;
    double a = 0.0;
    for (int i = t; i < NROWS / BN; i += 256) a += (double)partial[i];
    red[t] = a;
    __syncthreads();
    for (int mm = 128; mm > 0; mm >>= 1) {
        if (t < mm) red[t] += red[t + mm];
        __syncthreads();
    }
    if (t == 0) out_loss[0] = (float)(1.25 * red[0] / 8388608.0);
}

extern "C" void kernel_launch(void* const* d_in, const int* in_sizes, int n_in,
                              void* d_out, int out_size, void* d_ws, size_t ws_size,
                              hipStream_t stream) {
    const float* z = (const float*)d_in[0];
    const float* w = (const float*)d_in[1];
    float* out = (float*)d_out;

    char* ws = (char*)d_ws;
    float* wT = (float*)ws;                     // 8 MB
    float* A = (float*)(ws + 8388608);          // 128 KB
    float* Cq = (float*)(ws + 8519680);         // 32 KB
    int* idxi = (int*)(ws + 8552448);           // 128 KB
    float* partial = (float*)(ws + 8683520);    // 2 KB

    float* out_zq = out;                 // [B,C,T,H,W] = 8388608
    float* out_loss = out + 8388608;     // scalar
    float* out_idx = out + 8388609;      // [B,T,H,W] = 32768, as float

    k_T<<<512, 256, 0, stream>>>(w, wT);
    k_A<<<NROWS / 256, 256, 0, stream>>>(z, A);
    k_C<<<KDIM / 256, 256, 0, stream>>>(w, Cq);
    k_argmin<<<NROWS / BN, 256, 0, stream>>>(z, wT, A, Cq, out_idx, idxi);
    k_out<<<NROWS / BN, 256, 0, stream>>>(w, z, idxi, out_zq, partial);
    k_loss<<<1, 256, 0, stream>>>(partial, out_loss);
}

// Round 6
// 1451.256 us; speedup vs baseline: 1.4057x; 1.1537x over previous
//
#include <hip/hip_runtime.h>
#include <limits.h>

#define CDIM 256
#define KDIM 8192
#define NROWS 32768
#define THW 8192
#define BN 64      // rows per block (4 waves x 16 rows)

// ws layout (bytes):
//   [0,       8388608)  wT[c][k] = w[k][c]  (256 x 8192 f32)
//   [8388608, 8519680)  A[n]  (32768 f32)
//   [8519680, 8552448)  Cq[k] (8192 f32)
//   [8552448, 8683520)  idx_i (32768 i32)
//   [8683520, 8685568)  loss partials (512 f32)

__device__ __forceinline__ float sq_rn(float a) { return __fmul_rn(a, a); }

// numpy pairwise sum of 128 fp32 squares, AVX512 model (verified round 3).
__device__ float pairwise128_sq(const float* __restrict__ p, int stride) {
    float s[16];
#pragma unroll
    for (int l = 0; l < 16; ++l) {
        const float a0 = sq_rn(p[(l)*stride]);
        const float a1 = sq_rn(p[(16 + l) * stride]);
        const float a2 = sq_rn(p[(32 + l) * stride]);
        const float a3 = sq_rn(p[(48 + l) * stride]);
        const float a4 = sq_rn(p[(64 + l) * stride]);
        const float a5 = sq_rn(p[(80 + l) * stride]);
        const float a6 = sq_rn(p[(96 + l) * stride]);
        const float a7 = sq_rn(p[(112 + l) * stride]);
        s[l] = __fadd_rn(__fadd_rn(__fadd_rn(a0, a1), __fadd_rn(a2, a3)),
                         __fadd_rn(__fadd_rn(a4, a5), __fadd_rn(a6, a7)));
    }
    const float u0 = __fadd_rn(__fadd_rn(s[0], s[8]),  __fadd_rn(s[4], s[12]));
    const float u1 = __fadd_rn(__fadd_rn(s[1], s[9]),  __fadd_rn(s[5], s[13]));
    const float u2 = __fadd_rn(__fadd_rn(s[2], s[10]), __fadd_rn(s[6], s[14]));
    const float u3 = __fadd_rn(__fadd_rn(s[3], s[11]), __fadd_rn(s[7], s[15]));
    return __fadd_rn(__fadd_rn(u0, u2), __fadd_rn(u1, u3));
}

__global__ __launch_bounds__(256) void k_A(const float* __restrict__ z,
                                           float* __restrict__ A) {
    const int n = blockIdx.x * 256 + threadIdx.x;
    const float* zp = z + (size_t)(n >> 13) * (CDIM * THW) + (n & (THW - 1));
    const float b0 = pairwise128_sq(zp, THW);
    const float b1 = pairwise128_sq(zp + (size_t)128 * THW, THW);
    A[n] = __fadd_rn(b0, b1);
}

__global__ __launch_bounds__(256) void k_C(const float* __restrict__ w,
                                           float* __restrict__ Cq) {
    const int k = blockIdx.x * 256 + threadIdx.x;
    const float* wp = w + (size_t)k * CDIM;
    Cq[k] = __fadd_rn(pairwise128_sq(wp, 1), pairwise128_sq(wp + 128, 1));
}

// Transpose w[k][c] -> wT[c][k] via 64x64 LDS tiles.
__global__ __launch_bounds__(256) void k_T(const float* __restrict__ w,
                                           float* __restrict__ wT) {
    __shared__ float tile[64][65];
    const int t = threadIdx.x;
    const int kt = blockIdx.x >> 2;
    const int ct = blockIdx.x & 3;
    const int k0 = kt * 64, c0 = ct * 64;
    const int rg = t >> 4, cl = (t & 15) * 4;
#pragma unroll
    for (int i = 0; i < 4; ++i) {
        const int r = rg + i * 16;
        float4 v = *reinterpret_cast<const float4*>(w + (size_t)(k0 + r) * CDIM + c0 + cl);
        tile[r][cl] = v.x; tile[r][cl + 1] = v.y;
        tile[r][cl + 2] = v.z; tile[r][cl + 3] = v.w;
    }
    __syncthreads();
#pragma unroll
    for (int i = 0; i < 4; ++i) {
        const int cr = rg + i * 16;
        float4 o;
        o.x = tile[cl + 0][cr]; o.y = tile[cl + 1][cr];
        o.z = tile[cl + 2][cr]; o.w = tile[cl + 3][cr];
        *reinterpret_cast<float4*>(wT + (size_t)(c0 + cr) * KDIM + k0 + cl) = o;
    }
}

// p = kt*256 + c linear schedule position, 0..4095.
// w: lane owns k = kt*512 + lane*8 .. +7 (contiguous 64B/lane, coalesced,
// no in-wave duplication). z: wave-uniform LDS broadcast of 16 rows.
#define PREF_W(buf, p) { \
    const int pp_ = (p) < 4095 ? (p) : 4095; \
    const float* ap_ = wT + ((size_t)(pp_ & 255) << 13) + ((pp_ >> 8) << 9) + lane8; \
    buf[0] = *(const float4*)(ap_); \
    buf[1] = *(const float4*)(ap_ + 4); }

#define PREF_Z(buf, p) { \
    const float* zp_ = &zt[(p) & 255][wv16]; \
    buf[0] = *(const float4*)(zp_); \
    buf[1] = *(const float4*)(zp_ + 4); \
    buf[2] = *(const float4*)(zp_ + 8); \
    buf[3] = *(const float4*)(zp_ + 12); }

#define COMP(wb_, zb_) { \
    const float wr_[8] = {wb_[0].x, wb_[0].y, wb_[0].z, wb_[0].w, \
                          wb_[1].x, wb_[1].y, wb_[1].z, wb_[1].w}; \
    const float zr_[16] = {zb_[0].x, zb_[0].y, zb_[0].z, zb_[0].w, \
                           zb_[1].x, zb_[1].y, zb_[1].z, zb_[1].w, \
                           zb_[2].x, zb_[2].y, zb_[2].z, zb_[2].w, \
                           zb_[3].x, zb_[3].y, zb_[3].z, zb_[3].w}; \
    _Pragma("unroll") \
    for (int r_ = 0; r_ < 16; ++r_) \
        _Pragma("unroll") \
        for (int j_ = 0; j_ < 8; ++j_) \
            acc[r_][j_] = fmaf(zr_[r_], wr_[j_], acc[r_][j_]); }

// Fused scores GEMM + argmin, np-fp32-exact (verified round 3):
// single ascending-c fmaf chain; d = RN(RN(A-2M)+Cq); argmin ties->lowest k.
// 16 rows x 8 cols per thread; w register-streamed from wT through L1/L2;
// zero barriers in the main loop.
__global__ __launch_bounds__(256, 2) void k_argmin(
    const float* __restrict__ z, const float* __restrict__ wT,
    const float* __restrict__ A, const float* __restrict__ Cq,
    float* __restrict__ idx_f, int* __restrict__ idx_i)
{
    __shared__ float zt[CDIM][BN];   // 64 KB resident z tile [c][n]

    const int t = threadIdx.x;
    const int blk = blockIdx.x;
    const int b = (blk * BN) >> 13;
    const int s0 = (blk * BN) & (THW - 1);
    const float* zb = z + (size_t)b * (CDIM * THW) + s0;

    {   // load z tile (coalesced, once)
        const int lane = t & 15;
        const int c0 = t >> 4;
#pragma unroll
        for (int it = 0; it < 16; ++it) {
            const int c = c0 + it * 16;
            float4 v = *reinterpret_cast<const float4*>(zb + (size_t)c * THW + lane * 4);
            *reinterpret_cast<float4*>(&zt[c][lane * 4]) = v;
        }
    }
    __syncthreads();   // the only barrier

    const int lane8 = (t & 63) * 8;   // k-offset within k-tile
    const int wv16 = (t >> 6) * 16;   // row-offset within block
    const int nbase = blk * BN + wv16;

    float best[16];
    int bidx[16];
#pragma unroll
    for (int r = 0; r < 16; ++r) { best[r] = 3.0e38f; bidx[r] = INT_MAX; }

    float4 wa[2], wb[2], za[4], zb4[4];
    PREF_W(wa, 0); PREF_Z(za, 0);

    for (int kt = 0; kt < 16; ++kt) {
        float acc[16][8];
#pragma unroll
        for (int r = 0; r < 16; ++r)
#pragma unroll
            for (int j = 0; j < 8; ++j) acc[r][j] = 0.f;

        const int pbase = kt * 256;
        for (int c2 = 0; c2 < 256; c2 += 2) {
            PREF_W(wb, pbase + c2 + 1); PREF_Z(zb4, pbase + c2 + 1);
            COMP(wa, za);
            PREF_W(wa, pbase + c2 + 2); PREF_Z(za, pbase + c2 + 2);
            COMP(wb, zb4);
        }

        // epilogue: d = RN(RN(A - 2M) + C); ascending k; strict < (np.argmin)
        const float4 cq0 = *reinterpret_cast<const float4*>(Cq + kt * 512 + lane8);
        const float4 cq1 = *reinterpret_cast<const float4*>(Cq + kt * 512 + lane8 + 4);
        const float cv[8] = {cq0.x, cq0.y, cq0.z, cq0.w, cq1.x, cq1.y, cq1.z, cq1.w};
        float Ar[16];
#pragma unroll
        for (int r = 0; r < 16; ++r) Ar[r] = A[nbase + r];
#pragma unroll
        for (int j = 0; j < 8; ++j) {
            const int kg = kt * 512 + lane8 + j;
#pragma unroll
            for (int r = 0; r < 16; ++r) {
                const float dd = __fadd_rn(__fadd_rn(Ar[r], -2.0f * acc[r][j]), cv[j]);
                if (dd < best[r]) { best[r] = dd; bidx[r] = kg; }
            }
        }
    }

    // Merge across the 64 lanes (each lane had a disjoint k-set); ties -> lower k.
#pragma unroll
    for (int m = 1; m < 64; m <<= 1) {
#pragma unroll
        for (int r = 0; r < 16; ++r) {
            const float od = __shfl_xor(best[r], m, 64);
            const int oi = __shfl_xor(bidx[r], m, 64);
            if (od < best[r] || (od == best[r] && oi < bidx[r])) {
                best[r] = od; bidx[r] = oi;
            }
        }
    }
    if ((t & 63) == 0) {
#pragma unroll
        for (int r = 0; r < 16; ++r) {
            const int n = nbase + r;
            idx_f[n] = (float)bidx[r];
            idx_i[n] = bidx[r];
        }
    }
}

// Gather z_q = w[idx], transpose to [B,C,T,H,W], accumulate sum((z_q - z)^2).
__global__ __launch_bounds__(256, 2) void k_out(
    const float* __restrict__ w, const float* __restrict__ z,
    const int* __restrict__ idx, float* __restrict__ out0,
    float* __restrict__ partial)
{
    __shared__ float q[CDIM][BN + 1];
    __shared__ int si[BN];
    __shared__ float red[256];

    const int t = threadIdx.x;
    const int blk = blockIdx.x;
    const int n0 = blk * BN;
    const int b = n0 >> 13;
    const int s0 = n0 & (THW - 1);

    if (t < BN) si[t] = idx[n0 + t];
    __syncthreads();

    {
        const int c = t;
#pragma unroll 4
        for (int i = 0; i < BN; ++i)
            q[c][i] = w[(size_t)si[i] * CDIM + c];
    }
    __syncthreads();

    const int sl = t & 63;
    const int cb = t >> 6;
    float lacc = 0.f;
    const size_t base = (size_t)b * (CDIM * THW) + s0 + sl;
#pragma unroll 4
    for (int j = 0; j < 64; ++j) {
        const int c = cb * 64 + j;
        const float qv = q[c][sl];
        const size_t a = base + (size_t)c * THW;
        const float zv = z[a];
        out0[a] = qv;
        const float d = qv - zv;
        lacc = fmaf(d, d, lacc);
    }
    red[t] = lacc;
    __syncthreads();
    for (int mm = 128; mm > 0; mm >>= 1) {
        if (t < mm) red[t] += red[t + mm];
        __syncthreads();
    }
    if (t == 0) partial[blk] = red[0];
}

__global__ __launch_bounds__(256) void k_loss(const float* __restrict__ partial,
                                              float* __restrict__ out_loss) {
    __shared__ double red[256];
    const int t = threadIdx.x;
    double a = 0.0;
    for (int i = t; i < NROWS / BN; i += 256) a += (double)partial[i];
    red[t] = a;
    __syncthreads();
    for (int mm = 128; mm > 0; mm >>= 1) {
        if (t < mm) red[t] += red[t + mm];
        __syncthreads();
    }
    if (t == 0) out_loss[0] = (float)(1.25 * red[0] / 8388608.0);
}

extern "C" void kernel_launch(void* const* d_in, const int* in_sizes, int n_in,
                              void* d_out, int out_size, void* d_ws, size_t ws_size,
                              hipStream_t stream) {
    const float* z = (const float*)d_in[0];
    const float* w = (const float*)d_in[1];
    float* out = (float*)d_out;

    char* ws = (char*)d_ws;
    float* wT = (float*)ws;                     // 8 MB
    float* A = (float*)(ws + 8388608);          // 128 KB
    float* Cq = (float*)(ws + 8519680);         // 32 KB
    int* idxi = (int*)(ws + 8552448);           // 128 KB
    float* partial = (float*)(ws + 8683520);    // 2 KB

    float* out_zq = out;                 // [B,C,T,H,W] = 8388608
    float* out_loss = out + 8388608;     // scalar
    float* out_idx = out + 8388609;      // [B,T,H,W] = 32768, as float

    k_T<<<512, 256, 0, stream>>>(w, wT);
    k_A<<<NROWS / 256, 256, 0, stream>>>(z, A);
    k_C<<<KDIM / 256, 256, 0, stream>>>(w, Cq);
    k_argmin<<<NROWS / BN, 256, 0, stream>>>(z, wT, A, Cq, out_idx, idxi);
    k_out<<<NROWS / BN, 256, 0, stream>>>(w, z, idxi, out_zq, partial);
    k_loss<<<1, 256, 0, stream>>>(partial, out_loss);
}